// Round 5
// baseline (452.431 us; speedup 1.0000x reference)
//
#include <hip/hip_runtime.h>

typedef unsigned short u16;
typedef __attribute__((ext_vector_type(8))) __bf16 bf16x8;
typedef __attribute__((ext_vector_type(4))) float f32x4;
typedef __attribute__((ext_vector_type(8))) u16 u16x8;
typedef __attribute__((ext_vector_type(4))) u16 u16x4;

__device__ __forceinline__ float bf2f(u16 u) {
  return __builtin_bit_cast(float, ((unsigned)u) << 16);
}
__device__ __forceinline__ u16 f2bf(float f) {
  unsigned x = __builtin_bit_cast(unsigned, f);
  x += 0x7fffu + ((x >> 16) & 1u);
  return (u16)(x >> 16);
}
__device__ __forceinline__ f32x4 cvt4(u16x4 v) {
  return (f32x4){bf2f(v.x), bf2f(v.y), bf2f(v.z), bf2f(v.w)};
}
__device__ __forceinline__ void gload_lds16(const void* g, void* l) {
  __builtin_amdgcn_global_load_lds(
      (const __attribute__((address_space(1))) void*)g,
      (__attribute__((address_space(3))) void*)l, 16, 0, 0);
}

// ---- fused weight prep: Wt[n][k] = bf16(W[k][n]) for all 4 weight matrices ----
__global__ void prepw4_kernel(const float* __restrict__ W0, u16* __restrict__ T0,
                              const float* __restrict__ W1, u16* __restrict__ T1,
                              const float* __restrict__ W2, u16* __restrict__ T2,
                              const float* __restrict__ W3, u16* __restrict__ T3) {
  int i = blockIdx.x * 256 + threadIdx.x;
  const float* W; u16* T; int K, N;
  if (i < 65536)        { W = W0; T = T0; K = 256; N = 256; }
  else if (i < 131072)  { W = W1; T = T1; K = 256; N = 256; i -= 65536; }
  else if (i < 262144)  { W = W2; T = T2; K = 512; N = 256; i -= 131072; }
  else if (i < 327680)  { W = W3; T = T3; K = 512; N = 128; i -= 262144; }
  else return;
  int k = i / N, n = i - k * N;
  T[(size_t)n * K + k] = f2bf(W[i]);
}

// ---- x convert fp32 -> bf16 ----
__global__ void cvtx_kernel(const float* __restrict__ in, u16* __restrict__ out,
                            int total4) {
  int i = blockIdx.x * 256 + threadIdx.x;
  if (i >= total4) return;
  const float4 v = ((const float4*)in)[i];
  u16x4 o = { f2bf(v.x), f2bf(v.y), f2bf(v.z), f2bf(v.w) };
  ((u16x4*)out)[i] = o;
}

// ---- row pointer via binary search over sorted adj_rows ----
__global__ void rowptr_kernel(const int* __restrict__ rows, int nE,
                              int* __restrict__ rp, int nN) {
  int i = blockIdx.x * 256 + threadIdx.x;
  if (i > nN) return;
  int lo = 0, hi = nE;
  while (lo < hi) { int mid = (lo + hi) >> 1; if (rows[mid] < i) lo = mid + 1; else hi = mid; }
  rp[i] = lo;
}

// ---- spmm, col-range tiled: 8 passes over each node's edge list, gathering only
// cols in the current 1/8 range (~3.2MB of X -> L2-resident). Range test is
// wave-uniform (scalar branch). Chain slot = scan position & 3 (compile-time).
// Node's cols span ~1 L1 line -> re-scans are cheap.
__global__ __launch_bounds__(128) void spmm_kernel(
    const u16* __restrict__ X, const int* __restrict__ rp,
    const int* __restrict__ cols, const float* __restrict__ vals,
    u16* __restrict__ out, int nN, int tileSz) {
  int lane = threadIdx.x & 63;
  int node = blockIdx.x * 2 + (threadIdx.x >> 6);
  if (node >= nN) return;
  int e0 = rp[node], e1 = rp[node + 1];
  f32x4 s0 = {0.f, 0.f, 0.f, 0.f}, s1 = s0, s2 = s0, s3 = s0;
  const u16* xp = X + (size_t)lane * 4;

  for (int t = 0; t < 8; ++t) {
    const int clo = t * tileSz;
    const int chi = clo + tileSz;
    int e = e0;
    for (; e + 4 <= e1; e += 4) {
      int c0 = cols[e], c1 = cols[e + 1], c2 = cols[e + 2], c3 = cols[e + 3];
      if (c0 >= clo && c0 < chi) {
        float v = vals[e];
        s0 += v * cvt4(*(const u16x4*)(xp + (size_t)c0 * 256));
      }
      if (c1 >= clo && c1 < chi) {
        float v = vals[e + 1];
        s1 += v * cvt4(*(const u16x4*)(xp + (size_t)c1 * 256));
      }
      if (c2 >= clo && c2 < chi) {
        float v = vals[e + 2];
        s2 += v * cvt4(*(const u16x4*)(xp + (size_t)c2 * 256));
      }
      if (c3 >= clo && c3 < chi) {
        float v = vals[e + 3];
        s3 += v * cvt4(*(const u16x4*)(xp + (size_t)c3 * 256));
      }
    }
    for (; e < e1; ++e) {
      int c = cols[e];
      if (c >= clo && c < chi) {
        float v = vals[e];
        s0 += v * cvt4(*(const u16x4*)(xp + (size_t)c * 256));
      }
    }
  }
  f32x4 s = (s0 + s1) + (s2 + s3);
  u16x4 o = { f2bf(s.x), f2bf(s.y), f2bf(s.z), f2bf(s.w) };
  *(u16x4*)(out + (size_t)node * 256 + lane * 4) = o;
}

// ---- GEMM: out[M][N] = act( A[M][K] * W[K][N] + bias ), W transposed Wt[N][K] bf16.
// 128x128 tile, BK=64, 4 waves (2x2) x 64x64 wave tile, global_load_lds width 16,
// XOR-swizzled LDS (pre-swizzled global source + swizzled ds_read; LDS dest linear).
// DOUBLE-BUFFERED: stage tile kt+1 before computing tile kt.
// SPLIT: A = concat(A0, A1) along K. NORM: fused row-L2 normalize (needs N==128).
template<int KTOT, bool SPLIT, bool RELU, bool OUTF32, bool NORM>
__global__ __launch_bounds__(256) void gemm_kernel(
    const u16* __restrict__ A0, const u16* __restrict__ A1,
    const u16* __restrict__ Wt, const float* __restrict__ bias,
    void* __restrict__ outp, int M, int N) {
  __shared__ u16 As[2][128 * 64];  // [row][slot*8] swizzled: slot = kseg ^ (row&7)
  __shared__ u16 Bs[2][128 * 64];
  __shared__ float red[128][2];    // NORM cross-wave ss partials

  const int lane = threadIdx.x & 63;
  const int wid = threadIdx.x >> 6;
  const int wr = wid >> 1, wc = wid & 1;
  const int row0b = blockIdx.y * 128;
  const int col0b = blockIdx.x * 128;
  const int lr = lane & 15;   // fragment row (A) / col (B,D)
  const int kg = lane >> 4;   // k-group; D-row group

  const int u = (wid * 4) * 64 + lane;

  auto stage = [&](int buf, int kt) {
    const u16* Asrc = (!SPLIT || kt < 4) ? A0 : A1;
    const int kkl = (!SPLIT || kt < 4) ? kt * 64 : (kt - 4) * 64;
    #pragma unroll
    for (int i = 0; i < 4; ++i) {
      const int c = wid * 4 + i;
      const int uu = u + i * 64;
      const int row = uu >> 3;
      const int ksd = uu & 7;
      const int kss = ksd ^ (row & 7);
      int grow = row0b + row;
      if (grow >= M) grow = M - 1;
      gload_lds16(Asrc + (size_t)grow * 256 + kkl + kss * 8, &As[buf][c * 512]);
      gload_lds16(Wt + (size_t)(col0b + row) * KTOT + kt * 64 + kss * 8, &Bs[buf][c * 512]);
    }
  };

  f32x4 acc[4][4];
  #pragma unroll
  for (int ni = 0; ni < 4; ++ni) {
    float bv = bias[col0b + wc * 64 + ni * 16 + lr];
    #pragma unroll
    for (int mi = 0; mi < 4; ++mi) acc[mi][ni] = (f32x4){bv, bv, bv, bv};
  }

  constexpr int KSTEPS = KTOT / 64;
  stage(0, 0);
  __syncthreads();  // vmcnt(0) drain: tile 0 ready

  for (int kt = 0; kt < KSTEPS; ++kt) {
    const int cur = kt & 1;
    if (kt + 1 < KSTEPS) stage(cur ^ 1, kt + 1);  // prefetch next tile

    #pragma unroll
    for (int ks = 0; ks < 2; ++ks) {
      const int q = ks * 4 + kg;
      bf16x8 a[4], b[4];
      #pragma unroll
      for (int mi = 0; mi < 4; ++mi) {
        const int r = wr * 64 + mi * 16 + lr;
        a[mi] = __builtin_bit_cast(bf16x8,
            *(const u16x8*)&As[cur][r * 64 + (q ^ (r & 7)) * 8]);
      }
      #pragma unroll
      for (int ni = 0; ni < 4; ++ni) {
        const int cb = wc * 64 + ni * 16 + lr;
        b[ni] = __builtin_bit_cast(bf16x8,
            *(const u16x8*)&Bs[cur][cb * 64 + (q ^ (cb & 7)) * 8]);
      }
      #pragma unroll
      for (int mi = 0; mi < 4; ++mi)
        #pragma unroll
        for (int ni = 0; ni < 4; ++ni)
          acc[mi][ni] = __builtin_amdgcn_mfma_f32_16x16x32_bf16(a[mi], b[ni], acc[mi][ni], 0, 0, 0);
    }
    __syncthreads();  // prefetch landed + all waves done with buf[cur]
  }

  // --- fused row-L2 norm (requires full row in this block: N==128) ---
  float invn[4][4];
  if (NORM) {
    #pragma unroll
    for (int mi = 0; mi < 4; ++mi) {
      #pragma unroll
      for (int j = 0; j < 4; ++j) {
        float p = 0.f;
        #pragma unroll
        for (int ni = 0; ni < 4; ++ni) { float v = acc[mi][ni][j]; p += v * v; }
        #pragma unroll
        for (int m = 1; m < 16; m <<= 1) p += __shfl_xor(p, m, 64);
        int rl = wr * 64 + mi * 16 + kg * 4 + j;
        if (lr == 0) red[rl][wc] = p;
        invn[mi][j] = 0.f;
      }
    }
    __syncthreads();
    #pragma unroll
    for (int mi = 0; mi < 4; ++mi) {
      #pragma unroll
      for (int j = 0; j < 4; ++j) {
        int rl = wr * 64 + mi * 16 + kg * 4 + j;
        float ss = red[rl][0] + red[rl][1];
        float nrm = sqrtf(ss);
        nrm = nrm > 1e-12f ? nrm : 1e-12f;
        invn[mi][j] = 1.f / nrm;
      }
    }
  }

  // epilogue: D[r][c], r = row0b + wr*64 + mi*16 + kg*4 + j, c = col0b + wc*64 + ni*16 + lr
  #pragma unroll
  for (int mi = 0; mi < 4; ++mi) {
    #pragma unroll
    for (int j = 0; j < 4; ++j) {
      int r = row0b + wr * 64 + mi * 16 + kg * 4 + j;
      if (r >= M) continue;
      #pragma unroll
      for (int ni = 0; ni < 4; ++ni) {
        float v = acc[mi][ni][j];
        if (RELU) v = v > 0.f ? v : 0.f;
        if (NORM) v *= invn[mi][j];
        int c = col0b + wc * 64 + ni * 16 + lr;
        if (OUTF32) ((float*)outp)[(size_t)r * N + c] = v;
        else        ((u16*)outp)[(size_t)r * N + c] = f2bf(v);
      }
    }
  }
}

extern "C" void kernel_launch(void* const* d_in, const int* in_sizes, int n_in,
                              void* d_out, int out_size, void* d_ws, size_t ws_size,
                              hipStream_t stream) {
  const float* x        = (const float*)d_in[0];
  const int*   adj_rows = (const int*)d_in[1];
  const int*   adj_cols = (const int*)d_in[2];
  const float* adj_vals = (const float*)d_in[3];
  const float* Wa0 = (const float*)d_in[4];
  const float* ba0 = (const float*)d_in[5];
  const float* Wa1 = (const float*)d_in[6];
  const float* ba1 = (const float*)d_in[7];
  const float* Wl0 = (const float*)d_in[8];
  const float* bl0 = (const float*)d_in[9];
  const float* Wl1 = (const float*)d_in[10];
  const float* bl1 = (const float*)d_in[11];

  const int nN = in_sizes[0] / 256;
  const int nE = in_sizes[1];
  const int tileSz = (nN + 7) / 8;

  char* ws = (char*)d_ws;
  size_t off = 0;
  auto alloc = [&](size_t bytes) -> void* {
    void* p = ws + off;
    off += (bytes + 255) & ~(size_t)255;
    return p;
  };
  u16* x_bf  = (u16*)alloc((size_t)nN * 256 * 2);
  u16* aggA  = (u16*)alloc((size_t)nN * 256 * 2);
  u16* aggB  = (u16*)alloc((size_t)nN * 256 * 2);
  u16* h_bf  = (u16*)alloc((size_t)nN * 256 * 2);
  int* rp    = (int*)alloc((size_t)(nN + 1) * 4);
  u16* wt_a0 = (u16*)alloc(256 * 256 * 2);
  u16* wt_a1 = (u16*)alloc(256 * 256 * 2);
  u16* wt_l0 = (u16*)alloc(512 * 256 * 2);
  u16* wt_l1 = (u16*)alloc(512 * 128 * 2);
  if (off > ws_size) return;

  dim3 blk(256);
  prepw4_kernel<<<dim3(1280), blk, 0, stream>>>(Wa0, wt_a0, Wa1, wt_a1, Wl0, wt_l0, Wl1, wt_l1);
  cvtx_kernel<<<dim3((nN * 64 + 255) / 256), blk, 0, stream>>>(x, x_bf, nN * 64);
  rowptr_kernel<<<dim3((nN + 1 + 255) / 256), blk, 0, stream>>>(adj_rows, nE, rp, nN);

  const int MB = (nN + 127) / 128;
  dim3 gN256(2, MB);
  dim3 gN128(1, MB);
  dim3 gNode((nN + 1) / 2);
  dim3 sblk(128);

  // layer 0
  spmm_kernel<<<gNode, sblk, 0, stream>>>(x_bf, rp, adj_cols, adj_vals, aggA, nN, tileSz);
  gemm_kernel<256, false, true, false, false><<<gN256, blk, 0, stream>>>(aggA, nullptr, wt_a0, ba0, aggB, nN, 256);
  gemm_kernel<512, true, true, false, false><<<gN256, blk, 0, stream>>>(x_bf, aggB, wt_l0, bl0, h_bf, nN, 256);
  // layer 1
  spmm_kernel<<<gNode, sblk, 0, stream>>>(h_bf, rp, adj_cols, adj_vals, aggA, nN, tileSz);
  gemm_kernel<256, false, true, false, false><<<gN256, blk, 0, stream>>>(aggA, nullptr, wt_a1, ba1, aggB, nN, 256);
  // layer 1 linear + fused L2 normalize -> d_out (fp32)
  gemm_kernel<512, true, false, true, true><<<gN128, blk, 0, stream>>>(h_bf, aggB, wt_l1, bl1, (float*)d_out, nN, 128);
}

// Round 6
// 217.210 us; speedup vs baseline: 2.0829x; 2.0829x over previous
//
#include <hip/hip_runtime.h>

typedef unsigned short u16;
typedef __attribute__((ext_vector_type(8))) __bf16 bf16x8;
typedef __attribute__((ext_vector_type(4))) float f32x4;
typedef __attribute__((ext_vector_type(8))) u16 u16x8;
typedef __attribute__((ext_vector_type(4))) u16 u16x4;

__device__ __forceinline__ float bf2f(u16 u) {
  return __builtin_bit_cast(float, ((unsigned)u) << 16);
}
__device__ __forceinline__ u16 f2bf(float f) {
  unsigned x = __builtin_bit_cast(unsigned, f);
  x += 0x7fffu + ((x >> 16) & 1u);
  return (u16)(x >> 16);
}
__device__ __forceinline__ f32x4 cvt4(u16x4 v) {
  return (f32x4){bf2f(v.x), bf2f(v.y), bf2f(v.z), bf2f(v.w)};
}
__device__ __forceinline__ void gload_lds16(const void* g, void* l) {
  __builtin_amdgcn_global_load_lds(
      (const __attribute__((address_space(1))) void*)g,
      (__attribute__((address_space(3))) void*)l, 16, 0, 0);
}

// ---- fused weight prep: Wt[n][k] = bf16(W[k][n]) for all 4 weight matrices ----
__global__ void prepw4_kernel(const float* __restrict__ W0, u16* __restrict__ T0,
                              const float* __restrict__ W1, u16* __restrict__ T1,
                              const float* __restrict__ W2, u16* __restrict__ T2,
                              const float* __restrict__ W3, u16* __restrict__ T3) {
  int i = blockIdx.x * 256 + threadIdx.x;
  const float* W; u16* T; int K, N;
  if (i < 65536)        { W = W0; T = T0; K = 256; N = 256; }
  else if (i < 131072)  { W = W1; T = T1; K = 256; N = 256; i -= 65536; }
  else if (i < 262144)  { W = W2; T = T2; K = 512; N = 256; i -= 131072; }
  else if (i < 327680)  { W = W3; T = T3; K = 512; N = 128; i -= 262144; }
  else return;
  int k = i / N, n = i - k * N;
  T[(size_t)n * K + k] = f2bf(W[i]);
}

// ---- x convert fp32 -> bf16 ----
__global__ void cvtx_kernel(const float* __restrict__ in, u16* __restrict__ out,
                            int total4) {
  int i = blockIdx.x * 256 + threadIdx.x;
  if (i >= total4) return;
  const float4 v = ((const float4*)in)[i];
  u16x4 o = { f2bf(v.x), f2bf(v.y), f2bf(v.z), f2bf(v.w) };
  ((u16x4*)out)[i] = o;
}

// ---- row pointer via binary search over sorted adj_rows ----
__global__ void rowptr_kernel(const int* __restrict__ rows, int nE,
                              int* __restrict__ rp, int nN) {
  int i = blockIdx.x * 256 + threadIdx.x;
  if (i > nN) return;
  int lo = 0, hi = nE;
  while (lo < hi) { int mid = (lo + hi) >> 1; if (rows[mid] < i) lo = mid + 1; else hi = mid; }
  rp[i] = lo;
}

// ---- spmm: out[i][:] = sum_e vals[e] * X[cols[e]][:]  (bf16 in/out, fp32 acc)
// 8-deep clean unroll (8 outstanding 512B row-gathers/wave), 4 accumulation
// chains, 8/4/1 tail cascade. 128-thread blocks (2 nodes).
__global__ __launch_bounds__(128) void spmm_kernel(
    const u16* __restrict__ X, const int* __restrict__ rp,
    const int* __restrict__ cols, const float* __restrict__ vals,
    u16* __restrict__ out, int nN) {
  int lane = threadIdx.x & 63;
  int node = blockIdx.x * 2 + (threadIdx.x >> 6);
  if (node >= nN) return;
  int e0 = rp[node], e1 = rp[node + 1];
  f32x4 s0 = {0.f, 0.f, 0.f, 0.f}, s1 = s0, s2 = s0, s3 = s0;
  const u16* xp = X + (size_t)lane * 4;
  int e = e0;
  for (; e + 8 <= e1; e += 8) {
    int c[8]; float v[8]; u16x4 xv[8];
    #pragma unroll
    for (int i = 0; i < 8; ++i) { c[i] = cols[e + i]; v[i] = vals[e + i]; }
    #pragma unroll
    for (int i = 0; i < 8; ++i) xv[i] = *(const u16x4*)(xp + (size_t)c[i] * 256);
    s0 += v[0] * cvt4(xv[0]); s1 += v[1] * cvt4(xv[1]);
    s2 += v[2] * cvt4(xv[2]); s3 += v[3] * cvt4(xv[3]);
    s0 += v[4] * cvt4(xv[4]); s1 += v[5] * cvt4(xv[5]);
    s2 += v[6] * cvt4(xv[6]); s3 += v[7] * cvt4(xv[7]);
  }
  if (e + 4 <= e1) {
    int c0 = cols[e], c1 = cols[e + 1], c2 = cols[e + 2], c3 = cols[e + 3];
    float v0 = vals[e], v1 = vals[e + 1], v2 = vals[e + 2], v3 = vals[e + 3];
    u16x4 x0 = *(const u16x4*)(xp + (size_t)c0 * 256);
    u16x4 x1 = *(const u16x4*)(xp + (size_t)c1 * 256);
    u16x4 x2 = *(const u16x4*)(xp + (size_t)c2 * 256);
    u16x4 x3 = *(const u16x4*)(xp + (size_t)c3 * 256);
    s0 += v0 * cvt4(x0); s1 += v1 * cvt4(x1);
    s2 += v2 * cvt4(x2); s3 += v3 * cvt4(x3);
    e += 4;
  }
  for (; e < e1; ++e) {
    int c = cols[e];
    float v = vals[e];
    s0 += v * cvt4(*(const u16x4*)(xp + (size_t)c * 256));
  }
  f32x4 s = (s0 + s1) + (s2 + s3);
  u16x4 o = { f2bf(s.x), f2bf(s.y), f2bf(s.z), f2bf(s.w) };
  *(u16x4*)(out + (size_t)node * 256 + lane * 4) = o;
}

// ---- GEMM: out[M][N] = act( A[M][K] * W[K][N] + bias ), W transposed Wt[N][K] bf16.
// 128x128 tile, BK=64, 4 waves (2x2) x 64x64 wave tile, global_load_lds width 16,
// XOR-swizzled LDS, double-buffered (stage kt+1 before computing kt).
// NB=2: 1D grid with pair-on-XCD swizzle — the two col-blocks sharing A-rows are
// placed 8 dispatch slots apart (same XCD under round-robin) so the 2nd A read
// hits that XCD's L2 instead of L3. NB=1: plain 1D (N==128).
// SPLIT: A = concat(A0, A1) along K. NORM: fused row-L2 normalize (needs N==128).
template<int KTOT, bool SPLIT, bool RELU, bool OUTF32, bool NORM, int NB>
__global__ __launch_bounds__(256) void gemm_kernel(
    const u16* __restrict__ A0, const u16* __restrict__ A1,
    const u16* __restrict__ Wt, const float* __restrict__ bias,
    void* __restrict__ outp, int M, int N) {
  __shared__ u16 As[2][128 * 64];  // [row][slot*8] swizzled: slot = kseg ^ (row&7)
  __shared__ u16 Bs[2][128 * 64];
  __shared__ float red[128][2];    // NORM cross-wave ss partials

  const int lane = threadIdx.x & 63;
  const int wid = threadIdx.x >> 6;
  const int wr = wid >> 1, wc = wid & 1;

  int row0b, col0b;
  if (NB == 2) {
    const int b = blockIdx.x;
    const int g = b >> 4, w = b & 15;
    const int nfull = gridDim.x >> 4;
    int pair, col;
    if (g < nfull) { pair = g * 8 + (w & 7); col = w >> 3; }
    else { int rem = b - (nfull << 4); pair = nfull * 8 + (rem >> 1); col = rem & 1; }
    row0b = pair * 128; col0b = col * 128;
  } else {
    row0b = blockIdx.x * 128; col0b = 0;
  }

  const int lr = lane & 15;   // fragment row (A) / col (B,D)
  const int kg = lane >> 4;   // k-group; D-row group

  const int u = (wid * 4) * 64 + lane;

  auto stage = [&](int buf, int kt) {
    const u16* Asrc = (!SPLIT || kt < 4) ? A0 : A1;
    const int kkl = (!SPLIT || kt < 4) ? kt * 64 : (kt - 4) * 64;
    #pragma unroll
    for (int i = 0; i < 4; ++i) {
      const int c = wid * 4 + i;
      const int uu = u + i * 64;
      const int row = uu >> 3;
      const int ksd = uu & 7;
      const int kss = ksd ^ (row & 7);
      int grow = row0b + row;
      if (grow >= M) grow = M - 1;
      gload_lds16(Asrc + (size_t)grow * 256 + kkl + kss * 8, &As[buf][c * 512]);
      gload_lds16(Wt + (size_t)(col0b + row) * KTOT + kt * 64 + kss * 8, &Bs[buf][c * 512]);
    }
  };

  f32x4 acc[4][4];
  #pragma unroll
  for (int ni = 0; ni < 4; ++ni) {
    float bv = bias[col0b + wc * 64 + ni * 16 + lr];
    #pragma unroll
    for (int mi = 0; mi < 4; ++mi) acc[mi][ni] = (f32x4){bv, bv, bv, bv};
  }

  constexpr int KSTEPS = KTOT / 64;
  stage(0, 0);
  __syncthreads();  // vmcnt(0) drain: tile 0 ready

  for (int kt = 0; kt < KSTEPS; ++kt) {
    const int cur = kt & 1;
    if (kt + 1 < KSTEPS) stage(cur ^ 1, kt + 1);  // prefetch next tile

    #pragma unroll
    for (int ks = 0; ks < 2; ++ks) {
      const int q = ks * 4 + kg;
      bf16x8 a[4], b[4];
      #pragma unroll
      for (int mi = 0; mi < 4; ++mi) {
        const int r = wr * 64 + mi * 16 + lr;
        a[mi] = __builtin_bit_cast(bf16x8,
            *(const u16x8*)&As[cur][r * 64 + (q ^ (r & 7)) * 8]);
      }
      #pragma unroll
      for (int ni = 0; ni < 4; ++ni) {
        const int cb = wc * 64 + ni * 16 + lr;
        b[ni] = __builtin_bit_cast(bf16x8,
            *(const u16x8*)&Bs[cur][cb * 64 + (q ^ (cb & 7)) * 8]);
      }
      #pragma unroll
      for (int mi = 0; mi < 4; ++mi)
        #pragma unroll
        for (int ni = 0; ni < 4; ++ni)
          acc[mi][ni] = __builtin_amdgcn_mfma_f32_16x16x32_bf16(a[mi], b[ni], acc[mi][ni], 0, 0, 0);
    }
    __syncthreads();  // prefetch landed + all waves done with buf[cur]
  }

  // --- fused row-L2 norm (requires full row in this block: N==128) ---
  float invn[4][4];
  if (NORM) {
    #pragma unroll
    for (int mi = 0; mi < 4; ++mi) {
      #pragma unroll
      for (int j = 0; j < 4; ++j) {
        float p = 0.f;
        #pragma unroll
        for (int ni = 0; ni < 4; ++ni) { float v = acc[mi][ni][j]; p += v * v; }
        #pragma unroll
        for (int m = 1; m < 16; m <<= 1) p += __shfl_xor(p, m, 64);
        int rl = wr * 64 + mi * 16 + kg * 4 + j;
        if (lr == 0) red[rl][wc] = p;
        invn[mi][j] = 0.f;
      }
    }
    __syncthreads();
    #pragma unroll
    for (int mi = 0; mi < 4; ++mi) {
      #pragma unroll
      for (int j = 0; j < 4; ++j) {
        int rl = wr * 64 + mi * 16 + kg * 4 + j;
        float ss = red[rl][0] + red[rl][1];
        float nrm = sqrtf(ss);
        nrm = nrm > 1e-12f ? nrm : 1e-12f;
        invn[mi][j] = 1.f / nrm;
      }
    }
  }

  // epilogue: D[r][c], r = row0b + wr*64 + mi*16 + kg*4 + j, c = col0b + wc*64 + ni*16 + lr
  #pragma unroll
  for (int mi = 0; mi < 4; ++mi) {
    #pragma unroll
    for (int j = 0; j < 4; ++j) {
      int r = row0b + wr * 64 + mi * 16 + kg * 4 + j;
      if (r >= M) continue;
      #pragma unroll
      for (int ni = 0; ni < 4; ++ni) {
        float v = acc[mi][ni][j];
        if (RELU) v = v > 0.f ? v : 0.f;
        if (NORM) v *= invn[mi][j];
        int c = col0b + wc * 64 + ni * 16 + lr;
        if (OUTF32) ((float*)outp)[(size_t)r * N + c] = v;
        else        ((u16*)outp)[(size_t)r * N + c] = f2bf(v);
      }
    }
  }
}

extern "C" void kernel_launch(void* const* d_in, const int* in_sizes, int n_in,
                              void* d_out, int out_size, void* d_ws, size_t ws_size,
                              hipStream_t stream) {
  const float* x        = (const float*)d_in[0];
  const int*   adj_rows = (const int*)d_in[1];
  const int*   adj_cols = (const int*)d_in[2];
  const float* adj_vals = (const float*)d_in[3];
  const float* Wa0 = (const float*)d_in[4];
  const float* ba0 = (const float*)d_in[5];
  const float* Wa1 = (const float*)d_in[6];
  const float* ba1 = (const float*)d_in[7];
  const float* Wl0 = (const float*)d_in[8];
  const float* bl0 = (const float*)d_in[9];
  const float* Wl1 = (const float*)d_in[10];
  const float* bl1 = (const float*)d_in[11];

  const int nN = in_sizes[0] / 256;
  const int nE = in_sizes[1];

  char* ws = (char*)d_ws;
  size_t off = 0;
  auto alloc = [&](size_t bytes) -> void* {
    void* p = ws + off;
    off += (bytes + 255) & ~(size_t)255;
    return p;
  };
  u16* x_bf  = (u16*)alloc((size_t)nN * 256 * 2);
  u16* aggA  = (u16*)alloc((size_t)nN * 256 * 2);
  u16* aggB  = (u16*)alloc((size_t)nN * 256 * 2);
  u16* h_bf  = (u16*)alloc((size_t)nN * 256 * 2);
  int* rp    = (int*)alloc((size_t)(nN + 1) * 4);
  u16* wt_a0 = (u16*)alloc(256 * 256 * 2);
  u16* wt_a1 = (u16*)alloc(256 * 256 * 2);
  u16* wt_l0 = (u16*)alloc(512 * 256 * 2);
  u16* wt_l1 = (u16*)alloc(512 * 128 * 2);
  if (off > ws_size) return;

  dim3 blk(256);
  prepw4_kernel<<<dim3(1280), blk, 0, stream>>>(Wa0, wt_a0, Wa1, wt_a1, Wl0, wt_l0, Wl1, wt_l1);
  cvtx_kernel<<<dim3((nN * 64 + 255) / 256), blk, 0, stream>>>(x, x_bf, nN * 64);
  rowptr_kernel<<<dim3((nN + 1 + 255) / 256), blk, 0, stream>>>(adj_rows, nE, rp, nN);

  const int MB = (nN + 127) / 128;
  dim3 gN256(2 * MB);
  dim3 gN128(MB);
  dim3 gNode((nN + 1) / 2);
  dim3 sblk(128);

  // layer 0
  spmm_kernel<<<gNode, sblk, 0, stream>>>(x_bf, rp, adj_cols, adj_vals, aggA, nN);
  gemm_kernel<256, false, true, false, false, 2><<<gN256, blk, 0, stream>>>(aggA, nullptr, wt_a0, ba0, aggB, nN, 256);
  gemm_kernel<512, true, true, false, false, 2><<<gN256, blk, 0, stream>>>(x_bf, aggB, wt_l0, bl0, h_bf, nN, 256);
  // layer 1
  spmm_kernel<<<gNode, sblk, 0, stream>>>(h_bf, rp, adj_cols, adj_vals, aggA, nN);
  gemm_kernel<256, false, true, false, false, 2><<<gN256, blk, 0, stream>>>(aggA, nullptr, wt_a1, ba1, aggB, nN, 256);
  // layer 1 linear + fused L2 normalize -> d_out (fp32)
  gemm_kernel<512, true, false, true, true, 1><<<gN128, blk, 0, stream>>>(h_bf, aggB, wt_l1, bl1, (float*)d_out, nN, 128);
}